// Round 11
// baseline (439.692 us; speedup 1.0000x reference)
//
#include <hip/hip_runtime.h>
#include <stdint.h>

// GraphConvLayer: out[n,:] = W[type[n]] @ (A @ x)[n,:]
// N=16384, D=128, T=8.  A is 1 GiB f32 read exactly once -> HBM floor ~163us.
// Round 11 = Round 10's DMA + counted-vmcnt skeleton (best: 351us), with the
// two levers the R10 counters point at:
//  - LDS-read cut: 4-wave blocks, wave tile 32x64 (2 m-tiles x 4 n-tiles)
//    -> per-tile fragment reads 48KB -> 32KB (A-f32 redundancy 2x->2x over
//    half the waves, X redundancy 4x->2x).
//  - Lockstep break: SPLITK=2 -> 512 blocks -> 2 independent blocks/CU
//    (48KB LDS each); one block's LDS burst overlaps the other's vmcnt wait.
// Partials f32 -> g_part; R9's verified epilogue reduces + applies W in f32.

#define N_NODES 16384
#define DIM     128
#define NTYPES  8
#define BM      64
#define BK      32
#define SPLITK  2
#define KSLICE  (N_NODES / SPLITK)   // 8192
#define NIT_S   (KSLICE / BK)        // 256 tiles per block

typedef float  f32x4  __attribute__((ext_vector_type(4)));
typedef __bf16 bf16x8 __attribute__((ext_vector_type(8)));

__device__ __attribute__((aligned(16))) unsigned short g_xT[DIM * N_NODES];    // [d][n], 4 MiB bf16
__device__ __attribute__((aligned(16))) float g_part[SPLITK * N_NODES * DIM];  // 16 MiB f32 partials

__device__ __forceinline__ unsigned int f2b(float f) {
    unsigned int u = __float_as_uint(f);
    u += 0x7FFFu + ((u >> 16) & 1u);   // round-to-nearest-even
    return u >> 16;
}

__device__ __forceinline__ bf16x8 cvt8(const f32x4 lo, const f32x4 hi) {
    bf16x8 r;
    r[0] = (__bf16)lo[0]; r[1] = (__bf16)lo[1]; r[2] = (__bf16)lo[2]; r[3] = (__bf16)lo[3];
    r[4] = (__bf16)hi[0]; r[5] = (__bf16)hi[1]; r[6] = (__bf16)hi[2]; r[7] = (__bf16)hi[3];
    return r;
}

// ---------------- prep: x -> bf16 transposed [d][n] ----------------

__global__ void prep_xT(const float* __restrict__ x) {
    int n = blockIdx.x * 256 + threadIdx.x;          // 64 blocks x 256
    const float* row = x + (size_t)n * DIM;
#pragma unroll
    for (int d0 = 0; d0 < DIM; d0 += 4) {
        float4 v = *(const float4*)(row + d0);
        g_xT[(d0 + 0) * N_NODES + n] = (unsigned short)f2b(v.x);
        g_xT[(d0 + 1) * N_NODES + n] = (unsigned short)f2b(v.y);
        g_xT[(d0 + 2) * N_NODES + n] = (unsigned short)f2b(v.z);
        g_xT[(d0 + 3) * N_NODES + n] = (unsigned short)f2b(v.w);
    }
}

// ---------------- main GEMM kernel ----------------

#define ABYTES 8192   // A tile: 64 rows x 128B (8x16B chunks/row)
#define XBYTES 8192   // X tile: 128 d-rows x 64B (4x16B chunks/row)

#define GLOAD16(g, l) __builtin_amdgcn_global_load_lds(                         \
    (const __attribute__((address_space(1))) unsigned int*)(g),                 \
    (__attribute__((address_space(3))) unsigned int*)(l), 16, 0, 0)

// 4 DMA issues per wave per tile: A rounds 0/1 (rows 0-31 / 32-63),
// X rounds 0/1 (d 0-63 / 64-127); each round = 4 waves x 1KB linear dest.
#define DMA4(Ab, Xb) do {                          \
    GLOAD16(gA0, (Ab) + wq);                       \
    GLOAD16(gA1, (Ab) + 4096 + wq);                \
    GLOAD16(gX0, (Xb) + wq);                       \
    GLOAD16(gX1, (Xb) + 4096 + wq);                \
    gA0 += BK; gA1 += BK; gX0 += BK; gX1 += BK;    \
} while (0)

#define COMPUTE(Ab, Xb) do {                                                     \
    f32x4 _e0 = *(const f32x4*)((Ab) + ao0E);                                    \
    f32x4 _o0 = *(const f32x4*)((Ab) + ao0O);                                    \
    f32x4 _e1 = *(const f32x4*)((Ab) + ao0E + 2048);                             \
    f32x4 _o1 = *(const f32x4*)((Ab) + ao0O + 2048);                             \
    bf16x8 _af0 = cvt8(_e0, _o0);                                                \
    bf16x8 _af1 = cvt8(_e1, _o1);                                                \
    bf16x8 _b0 = *(const bf16x8*)((Xb) + xo0);                                   \
    bf16x8 _b1 = *(const bf16x8*)((Xb) + xo0 + 1024);                            \
    bf16x8 _b2 = *(const bf16x8*)((Xb) + xo0 + 2048);                            \
    bf16x8 _b3 = *(const bf16x8*)((Xb) + xo0 + 3072);                            \
    acc00 = __builtin_amdgcn_mfma_f32_16x16x32_bf16(_af0, _b0, acc00, 0, 0, 0);  \
    acc01 = __builtin_amdgcn_mfma_f32_16x16x32_bf16(_af0, _b1, acc01, 0, 0, 0);  \
    acc02 = __builtin_amdgcn_mfma_f32_16x16x32_bf16(_af0, _b2, acc02, 0, 0, 0);  \
    acc03 = __builtin_amdgcn_mfma_f32_16x16x32_bf16(_af0, _b3, acc03, 0, 0, 0);  \
    acc10 = __builtin_amdgcn_mfma_f32_16x16x32_bf16(_af1, _b0, acc10, 0, 0, 0);  \
    acc11 = __builtin_amdgcn_mfma_f32_16x16x32_bf16(_af1, _b1, acc11, 0, 0, 0);  \
    acc12 = __builtin_amdgcn_mfma_f32_16x16x32_bf16(_af1, _b2, acc12, 0, 0, 0);  \
    acc13 = __builtin_amdgcn_mfma_f32_16x16x32_bf16(_af1, _b3, acc13, 0, 0, 0);  \
} while (0)

// phase: counted vmcnt (tile t's 4 DMAs done; t+1's 4 in flight) -> barrier ->
// issue t+2 -> compute t.
#define PHASE_I(Ac, Xc, Ai, Xi, VM) do {                     \
    asm volatile("s_waitcnt vmcnt(" VM ")" ::: "memory");    \
    __builtin_amdgcn_s_barrier();                            \
    DMA4(Ai, Xi);                                            \
    COMPUTE(Ac, Xc);                                         \
} while (0)

#define PHASE_N(Ac, Xc, VM) do {                             \
    asm volatile("s_waitcnt vmcnt(" VM ")" ::: "memory");    \
    __builtin_amdgcn_s_barrier();                            \
    COMPUTE(Ac, Xc);                                         \
} while (0)

__global__ __launch_bounds__(256, 2) void gconv_main(const float* __restrict__ adj)
{
    __shared__ __align__(16) unsigned char lds[3 * (ABYTES + XBYTES)]; // 49152 B
    unsigned char* A0 = lds;
    unsigned char* A1 = lds + ABYTES;
    unsigned char* A2 = lds + 2 * ABYTES;
    unsigned char* X0 = lds + 3 * ABYTES;
    unsigned char* X1 = X0 + XBYTES;
    unsigned char* X2 = X0 + 2 * XBYTES;

    const int tid  = threadIdx.x;
    const int w    = tid >> 6;                    // 0..3
    const int l    = tid & 63;
    const int ks   = blockIdx.x & 1;              // k-slice
    const int m0   = (blockIdx.x >> 1) * BM;      // row block
    const int kb   = ks * KSLICE;

    const int mrow = (w & 1) * 32;                // wave: 32 rows x 64 cols
    const int ncol = (w >> 1) * 64;

    f32x4 acc00 = {}, acc01 = {}, acc02 = {}, acc03 = {},
          acc10 = {}, acc11 = {}, acc12 = {}, acc13 = {};

    // ---- DMA per-lane source pointers (pre-swizzled so linear LDS dest +
    // XOR'd read offsets give a consistent involution, m173/T2) ----
    // A round j: row = j*32 + 8w + (l>>3), chunk = (l&7) ^ (row&7)  [row&7 = l>>3]
    const float* gA0 = adj + (size_t)(m0 + 8 * w + (l >> 3)) * N_NODES + kb
                     + (((l & 7) ^ (l >> 3)) << 2);
    const float* gA1 = adj + (size_t)(m0 + 32 + 8 * w + (l >> 3)) * N_NODES + kb
                     + (((l & 7) ^ (l >> 3)) << 2);
    // X round j: d = j*64 + 16w + (l>>2), chunk = (l&3) ^ ((d>>1)&3)  [= (l>>3)&3]
    const unsigned short* gX0 = g_xT + (size_t)(16 * w + (l >> 2)) * N_NODES + kb
                              + (((l & 3) ^ ((l >> 3) & 3)) << 3);
    const unsigned short* gX1 = g_xT + (size_t)(64 + 16 * w + (l >> 2)) * N_NODES + kb
                              + (((l & 3) ^ ((l >> 3) & 3)) << 3);
    const int wq = w << 10;    // wave's 1KB slot within each round's 4KB

    // ---- compute-side byte offsets (XOR matches the source swizzle) ----
    // A: row = mrow + mt*16 + (l&15); logical chunks 2*(l>>4), +1; key row&7 = l&7
    const int ce   = (l >> 4) << 1;
    const int ao0E = (mrow + (l & 15)) * 128 + ((ce ^ (l & 7)) << 4);
    const int ao0O = (mrow + (l & 15)) * 128 + (((ce + 1) ^ (l & 7)) << 4);
    // X: d = ncol + nt*16 + (l&15); granule (l>>4) ^ ((d>>1)&3) [= (l>>1)&3]
    const int xo0  = (ncol + (l & 15)) * 64 + (((l >> 4) ^ ((l >> 1) & 3)) << 4);

    // ---- prologue: tiles 0,1 in flight (8 DMAs/wave outstanding) ----
    DMA4(A0, X0);
    DMA4(A1, X1);

    // ---- 256 phases: 84 x 3 steady + 4 tail ----
    for (int j = 0; j < 84; ++j) {
        PHASE_I(A0, X0, A2, X2, "4");   // t=3j
        PHASE_I(A1, X1, A0, X0, "4");   // t=3j+1
        PHASE_I(A2, X2, A1, X1, "4");   // t=3j+2
    }
    PHASE_I(A0, X0, A2, X2, "4");       // t=252, issue 254 -> buf2
    PHASE_I(A1, X1, A0, X0, "4");       // t=253, issue 255 -> buf0
    PHASE_N(A2, X2, "4");               // t=254
    PHASE_N(A0, X0, "0");               // t=255

    // ---- partial store: f32 accumulators -> g_part[ks] ----
    // C/D layout: col = lane&15, row = (lane>>4)*4 + reg
    float* pp0 = g_part + (size_t)ks * (N_NODES * DIM)
               + (size_t)(m0 + mrow + (l >> 4) * 4) * DIM + ncol + (l & 15);
    float* pp1 = pp0 + 16 * DIM;   // mt=1
#define STACC(p, nt, av) do {                  \
    (p)[0 * DIM + (nt) * 16] = av[0];          \
    (p)[1 * DIM + (nt) * 16] = av[1];          \
    (p)[2 * DIM + (nt) * 16] = av[2];          \
    (p)[3 * DIM + (nt) * 16] = av[3];          \
} while (0)
    STACC(pp0, 0, acc00); STACC(pp0, 1, acc01); STACC(pp0, 2, acc02); STACC(pp0, 3, acc03);
    STACC(pp1, 0, acc10); STACC(pp1, 1, acc11); STACC(pp1, 2, acc12); STACC(pp1, 3, acc13);
#undef STACC
}

// ---------------- epilogue: reduce partials + W[type] projection (f32) ----------------

__global__ __launch_bounds__(256) void gconv_epi(
    const float* __restrict__ wt,
    const int* __restrict__ types,
    float* __restrict__ out)
{
    __shared__ __align__(16) float agg[BM * 132];   // 33792 B

    const int tid  = threadIdx.x;
    const int w    = tid >> 6;
    const int lane = tid & 63;
    const int m0   = blockIdx.x * BM;

    // phase 1: agg[node][d] = part0 + part1
#pragma unroll
    for (int j = 0; j < 8; ++j) {
        const int f    = tid + j * 256;        // float4 index within 64x128 tile
        const int node = f >> 5;
        const int d4   = (f & 31) * 4;
        const float* p = g_part + (size_t)(m0 + node) * DIM + d4;
        float4 s0 = *(const float4*)(p);
        float4 s1 = *(const float4*)(p + (size_t)N_NODES * DIM);
        float4 s; s.x = s0.x + s1.x; s.y = s0.y + s1.y;
        s.z = s0.z + s1.z; s.w = s0.w + s1.w;
        *(float4*)&agg[node * 132 + d4] = s;
    }
    __syncthreads();

    // phase 2: out[n] = W[type[n]] @ agg[n]  (f32, lane -> 2 output features)
    const int rbase = w * 16;   // 16 nodes per wave
    for (int rr = 0; rr < 16; ++rr) {
        const int rw = rbase + rr;
        const int nn = m0 + rw;
        const int ty = types[nn];                       // wave-uniform
        const float* Wt = wt + (size_t)ty * DIM * DIM;
        const int o0 = lane * 2;
        const float* aggRow = agg + rw * 132;
        float s0 = 0.f, s1 = 0.f;
#pragma unroll
        for (int d0 = 0; d0 < DIM; d0 += 8) {
            float4 ga = *(const float4*)(aggRow + d0);
            float4 gb = *(const float4*)(aggRow + d0 + 4);
            float4 wa0 = *(const float4*)(Wt + (size_t)o0 * DIM + d0);
            float4 wa1 = *(const float4*)(Wt + (size_t)o0 * DIM + d0 + 4);
            float4 wb0 = *(const float4*)(Wt + (size_t)(o0 + 1) * DIM + d0);
            float4 wb1 = *(const float4*)(Wt + (size_t)(o0 + 1) * DIM + d0 + 4);
            s0 += ga.x * wa0.x + ga.y * wa0.y + ga.z * wa0.z + ga.w * wa0.w;
            s0 += gb.x * wa1.x + gb.y * wa1.y + gb.z * wa1.z + gb.w * wa1.w;
            s1 += ga.x * wb0.x + ga.y * wb0.y + ga.z * wb0.z + ga.w * wb0.w;
            s1 += gb.x * wb1.x + gb.y * wb1.y + gb.z * wb1.z + gb.w * wb1.w;
        }
        float2 res; res.x = s0; res.y = s1;
        *(float2*)(out + (size_t)nn * DIM + o0) = res;
    }
}

// ---------------- launch ----------------

extern "C" void kernel_launch(void* const* d_in, const int* in_sizes, int n_in,
                              void* d_out, int out_size, void* d_ws, size_t ws_size,
                              hipStream_t stream) {
    const float* x     = (const float*)d_in[0];
    const int*   types = (const int*)d_in[1];
    const float* adj   = (const float*)d_in[2];
    const float* wt    = (const float*)d_in[3];
    float* out = (float*)d_out;

    hipLaunchKernelGGL(prep_xT, dim3(64), dim3(256), 0, stream, x);
    hipLaunchKernelGGL(gconv_main, dim3((N_NODES / BM) * SPLITK), dim3(256), 0, stream, adj);
    hipLaunchKernelGGL(gconv_epi, dim3(N_NODES / BM), dim3(256), 0, stream, wt, types, out);
}

// Round 12
// 366.755 us; speedup vs baseline: 1.1989x; 1.1989x over previous
//
#include <hip/hip_runtime.h>
#include <stdint.h>

// GraphConvLayer: out[n,:] = W[type[n]] @ (A @ x)[n,:]
// N=16384, D=128, T=8.  A is 1 GiB f32 read exactly once -> HBM floor ~163us.
// Round 12 = Round 10 (best, 351us) with DMA pipeline depth 2 -> 5.
// R10/R11 post-mortem: barrier-locked phases make DMA issue bursty; with only
// 2 tiles (32KB) in flight the HBM queue drains each phase -> measured
// ~3.1TB/s (half of achievable). Six buffers, issue 5 tiles ahead, steady
// s_waitcnt vmcnt(8): ~80KB/CU continuously outstanding (3.5x the
// latency-BW product). Compute + swizzle identical to R10 (absmax 16).

#define N_NODES 16384
#define DIM     128
#define NTYPES  8
#define BM      64
#define BK      32
#define NIT     (N_NODES / BK)   // 512

typedef float  f32x4  __attribute__((ext_vector_type(4)));
typedef __bf16 bf16x8 __attribute__((ext_vector_type(8)));

__device__ __attribute__((aligned(16))) unsigned short g_xT[DIM * N_NODES];      // [d][n], 4 MiB bf16
__device__ __attribute__((aligned(16))) unsigned short g_Wb[NTYPES * DIM * DIM]; // [t][o][d], 256 KiB

__device__ __forceinline__ unsigned int f2b(float f) {
    unsigned int u = __float_as_uint(f);
    u += 0x7FFFu + ((u >> 16) & 1u);   // round-to-nearest-even
    return u >> 16;
}
#define BF_LO(u) __uint_as_float((unsigned int)(u) << 16)
#define BF_HI(u) __uint_as_float((unsigned int)(u) & 0xFFFF0000u)

__device__ __forceinline__ bf16x8 cvt8(const f32x4 lo, const f32x4 hi) {
    bf16x8 r;
    r[0] = (__bf16)lo[0]; r[1] = (__bf16)lo[1]; r[2] = (__bf16)lo[2]; r[3] = (__bf16)lo[3];
    r[4] = (__bf16)hi[0]; r[5] = (__bf16)hi[1]; r[6] = (__bf16)hi[2]; r[7] = (__bf16)hi[3];
    return r;
}

// ---------------- fused prep kernel ----------------
// blocks 0..63: xT transpose+convert; blocks 64..95: W convert.

__global__ void prep_all(const float* __restrict__ x, const float* __restrict__ w) {
    const int tid = threadIdx.x;
    if (blockIdx.x < 64) {
        int n = blockIdx.x * 256 + tid;
        const float* row = x + (size_t)n * DIM;
#pragma unroll
        for (int d0 = 0; d0 < DIM; d0 += 4) {
            float4 v = *(const float4*)(row + d0);
            g_xT[(d0 + 0) * N_NODES + n] = (unsigned short)f2b(v.x);
            g_xT[(d0 + 1) * N_NODES + n] = (unsigned short)f2b(v.y);
            g_xT[(d0 + 2) * N_NODES + n] = (unsigned short)f2b(v.z);
            g_xT[(d0 + 3) * N_NODES + n] = (unsigned short)f2b(v.w);
        }
    } else {
        int base = ((blockIdx.x - 64) * 256 + tid) * 16;
#pragma unroll
        for (int j = 0; j < 4; ++j) {
            float4 v = *(const float4*)(w + base + j * 4);
            ushort4 o;
            o.x = (unsigned short)f2b(v.x); o.y = (unsigned short)f2b(v.y);
            o.z = (unsigned short)f2b(v.z); o.w = (unsigned short)f2b(v.w);
            *(ushort4*)(g_Wb + base + j * 4) = o;
        }
    }
}

// ---------------- main fused kernel ----------------

#define ABYTES 8192   // A tile: 64 rows x 32 f32 (128B rows, 8x16B chunks)
#define XBYTES 8192   // X tile: 128 d-rows x 32 bf16 (64B rows, 4x16B chunks)
#define NBUF   6

#define GLOAD16(g, l) __builtin_amdgcn_global_load_lds(                         \
    (const __attribute__((address_space(1))) unsigned int*)(g),                 \
    (__attribute__((address_space(3))) unsigned int*)(l), 16, 0, 0)

#define COMPUTE(Ab, Xb) do {                                                    \
    f32x4 _lo = *(const f32x4*)((Ab) + aoE);                                    \
    f32x4 _hi = *(const f32x4*)((Ab) + aoO);                                    \
    bf16x8 _af = cvt8(_lo, _hi);                                                \
    bf16x8 _b0 = *(const bf16x8*)((Xb) + xbase);                                \
    bf16x8 _b1 = *(const bf16x8*)((Xb) + xbase + 1024);                         \
    bf16x8 _b2 = *(const bf16x8*)((Xb) + xbase + 2048);                         \
    bf16x8 _b3 = *(const bf16x8*)((Xb) + xbase + 3072);                         \
    acc0 = __builtin_amdgcn_mfma_f32_16x16x32_bf16(_af, _b0, acc0, 0, 0, 0);    \
    acc1 = __builtin_amdgcn_mfma_f32_16x16x32_bf16(_af, _b1, acc1, 0, 0, 0);    \
    acc2 = __builtin_amdgcn_mfma_f32_16x16x32_bf16(_af, _b2, acc2, 0, 0, 0);    \
    acc3 = __builtin_amdgcn_mfma_f32_16x16x32_bf16(_af, _b3, acc3, 0, 0, 0);    \
} while (0)

// phase: counted vmcnt (tile t's 2 DMAs done; t+1..t+4 in flight) -> barrier
// (all waves consumed tile t-1, whose buffer t+5 will overwrite) ->
// issue t+5 -> compute t.
#define PHASE_I(Ac, Xc, Ai, Xi, VM) do {                                        \
    asm volatile("s_waitcnt vmcnt(" VM ")" ::: "memory");                       \
    __builtin_amdgcn_s_barrier();                                               \
    GLOAD16(gAp, (Ai) + wq);                                                    \
    GLOAD16(gXp, (Xi) + wq);                                                    \
    gAp += BK; gXp += BK;                                                       \
    COMPUTE(Ac, Xc);                                                            \
} while (0)

#define PHASE_N(Ac, Xc, VM) do {                                                \
    asm volatile("s_waitcnt vmcnt(" VM ")" ::: "memory");                       \
    __builtin_amdgcn_s_barrier();                                               \
    COMPUTE(Ac, Xc);                                                            \
} while (0)

__global__ __launch_bounds__(512, 1) void gconv_main(
    const float* __restrict__ adj,
    const int* __restrict__ types,
    float* __restrict__ out)
{
    __shared__ __align__(16) unsigned char lds[NBUF * (ABYTES + XBYTES)]; // 98304 B
    unsigned char* A0 = lds;
    unsigned char* A1 = lds + 1 * ABYTES;
    unsigned char* A2 = lds + 2 * ABYTES;
    unsigned char* A3 = lds + 3 * ABYTES;
    unsigned char* A4 = lds + 4 * ABYTES;
    unsigned char* A5 = lds + 5 * ABYTES;
    unsigned char* X0 = lds + NBUF * ABYTES;
    unsigned char* X1 = X0 + 1 * XBYTES;
    unsigned char* X2 = X0 + 2 * XBYTES;
    unsigned char* X3 = X0 + 3 * XBYTES;
    unsigned char* X4 = X0 + 4 * XBYTES;
    unsigned char* X5 = X0 + 5 * XBYTES;

    const int tid  = threadIdx.x;
    const int w    = tid >> 6;          // 0..7
    const int l    = tid & 63;
    const int m0   = blockIdx.x * BM;

    const int mrow = (w & 3) * 16;      // wave's 16 output rows (of 64)
    const int ncol = (w >> 2) * 64;     // wave's 64 output cols (of 128)

    f32x4 acc0 = {}, acc1 = {}, acc2 = {}, acc3 = {};

    // ---- DMA per-lane source pointers (pre-swizzled, m173) ----
    // A call (1KB = 8 rows x 128B): row = 8w+(l>>3), src chunk = (l&7)^(l>>3)
    const float* gAp = adj + (size_t)(m0 + 8 * w + (l >> 3)) * N_NODES
                     + (((l & 7) ^ (l >> 3)) << 2);
    // X call (1KB = 16 d-rows x 64B): d = 16w+(l>>2), src chunk = (l&3)^((l>>3)&3)
    const unsigned short* gXp = g_xT + (size_t)(16 * w + (l >> 2)) * N_NODES
                              + (((l & 3) ^ ((l >> 3) & 3)) << 3);
    const int wq = w << 10;             // this wave's 1KB slot in each buffer

    // ---- compute-side per-lane byte offsets (XOR matches DMA swizzle) ----
    const int arow = mrow + (l & 15);
    const int ce   = (l >> 4) << 1;                       // logical A chunk (even)
    const int aoE  = arow * 128 + ((ce ^ (l & 7)) << 4);
    const int aoO  = arow * 128 + (((ce + 1) ^ (l & 7)) << 4);
    const int xph  = (l >> 4) ^ (((l & 15) >> 1) & 3);    // physical X chunk
    const int xbase = (ncol + (l & 15)) * 64 + (xph << 4);  // + nt*1024 per frag

    // ---- prologue: tiles 0..4 in flight (10 DMAs/wave outstanding) ----
    GLOAD16(gAp, A0 + wq); GLOAD16(gXp, X0 + wq); gAp += BK; gXp += BK;
    GLOAD16(gAp, A1 + wq); GLOAD16(gXp, X1 + wq); gAp += BK; gXp += BK;
    GLOAD16(gAp, A2 + wq); GLOAD16(gXp, X2 + wq); gAp += BK; gXp += BK;
    GLOAD16(gAp, A3 + wq); GLOAD16(gXp, X3 + wq); gAp += BK; gXp += BK;
    GLOAD16(gAp, A4 + wq); GLOAD16(gXp, X4 + wq); gAp += BK; gXp += BK;

    // ---- 512 phases: 84 x 6 steady (t=0..503) + 3 issuing + 5 tail ----
    for (int j = 0; j < 84; ++j) {
        PHASE_I(A0, X0, A5, X5, "8");   // t=6j   : compute buf0, issue t+5 -> buf5
        PHASE_I(A1, X1, A0, X0, "8");
        PHASE_I(A2, X2, A1, X1, "8");
        PHASE_I(A3, X3, A2, X2, "8");
        PHASE_I(A4, X4, A3, X3, "8");
        PHASE_I(A5, X5, A4, X4, "8");
    }
    PHASE_I(A0, X0, A5, X5, "8");       // t=504, issue 509 -> buf5
    PHASE_I(A1, X1, A0, X0, "8");       // t=505, issue 510 -> buf0
    PHASE_I(A2, X2, A1, X1, "8");       // t=506, issue 511 -> buf1
    PHASE_N(A3, X3, "8");               // t=507 (508..511 in flight)
    PHASE_N(A4, X4, "6");               // t=508
    PHASE_N(A5, X5, "4");               // t=509
    PHASE_N(A0, X0, "2");               // t=510
    PHASE_N(A1, X1, "0");               // t=511
    __syncthreads();                    // full drain before reusing LDS as agg

    // ---- epilogue: acc -> LDS agg (f32), then per-row W[type] dots ----
    float* agg = (float*)lds;   // [64][132] = 33792 B
#pragma unroll
    for (int r = 0; r < 4; ++r) {
        const int gr = (mrow + (l >> 4) * 4 + r) * 132 + ncol + (l & 15);
        agg[gr +  0] = acc0[r];
        agg[gr + 16] = acc1[r];
        agg[gr + 32] = acc2[r];
        agg[gr + 48] = acc3[r];
    }
    __syncthreads();

    const int rbase = w * 8;   // 8 rows per wave
    for (int rr = 0; rr < 8; ++rr) {
        const int rw = rbase + rr;
        const int nn = m0 + rw;
        const int ty = types[nn];                      // wave-uniform
        const unsigned short* Wt = g_Wb + ty * (DIM * DIM);
        const int o0 = l * 2;
        const float* aggRow = agg + rw * 132;
        float s0 = 0.f, s1 = 0.f;
#pragma unroll
        for (int d0 = 0; d0 < DIM; d0 += 8) {
            float4 ga = *(const float4*)(aggRow + d0);
            float4 gb = *(const float4*)(aggRow + d0 + 4);
            uint4 wa = *(const uint4*)(Wt + o0 * DIM + d0);
            uint4 wb = *(const uint4*)(Wt + (o0 + 1) * DIM + d0);
            s0 += ga.x * BF_LO(wa.x) + ga.y * BF_HI(wa.x) + ga.z * BF_LO(wa.y) + ga.w * BF_HI(wa.y);
            s0 += gb.x * BF_LO(wa.z) + gb.y * BF_HI(wa.z) + gb.z * BF_LO(wa.w) + gb.w * BF_HI(wa.w);
            s1 += ga.x * BF_LO(wb.x) + ga.y * BF_HI(wb.x) + ga.z * BF_LO(wb.y) + ga.w * BF_HI(wb.y);
            s1 += gb.x * BF_LO(wb.z) + gb.y * BF_HI(wb.z) + gb.z * BF_LO(wb.w) + gb.w * BF_HI(wb.w);
        }
        float2 res; res.x = s0; res.y = s1;
        *(float2*)(out + (size_t)nn * DIM + o0) = res;
    }
}

// ---------------- launch ----------------

extern "C" void kernel_launch(void* const* d_in, const int* in_sizes, int n_in,
                              void* d_out, int out_size, void* d_ws, size_t ws_size,
                              hipStream_t stream) {
    const float* x     = (const float*)d_in[0];
    const int*   types = (const int*)d_in[1];
    const float* adj   = (const float*)d_in[2];
    const float* wt    = (const float*)d_in[3];
    float* out = (float*)d_out;

    hipLaunchKernelGGL(prep_all, dim3(96), dim3(256), 0, stream, x, wt);
    hipLaunchKernelGGL(gconv_main, dim3(N_NODES / BM), dim3(512), 0, stream, adj, types, out);
}

// Round 13
// 310.363 us; speedup vs baseline: 1.4167x; 1.1817x over previous
//
#include <hip/hip_runtime.h>
#include <stdint.h>

// GraphConvLayer: out[n,:] = W[type[n]] @ (A @ x)[n,:]
// N=16384, D=128, T=8.  A is 1 GiB f32 read exactly once -> HBM floor ~163us.
// Round 13 = Round 10's DMA + counted-vmcnt skeleton with BK 32 -> 128.
// R3/R10/R12 all sit at ~2x the HBM floor regardless of structure; fill
// kernels (sequential) hit 6.5TB/s. Theory: 128B-per-row-per-tile touches
// across 16384 chip-wide streams thrash DRAM pages. BK=128 -> 512B bursts
// per row per tile + 4x fewer barrier phases (512 -> 128).
// 2 buffers x (A 32KB f32 + X 32KB bf16) = 128KB LDS; two barriers/phase:
// vmcnt(8) -> bar -> compute(16 MFMA) -> bar -> issue t+2 (8 DMA calls).

#define N_NODES 16384
#define DIM     128
#define NTYPES  8
#define BM      64
#define BK      128
#define NT_K    (N_NODES / BK)   // 128 tiles

typedef float  f32x4  __attribute__((ext_vector_type(4)));
typedef __bf16 bf16x8 __attribute__((ext_vector_type(8)));

__device__ __attribute__((aligned(16))) unsigned short g_xT[DIM * N_NODES];      // [d][n], 4 MiB bf16
__device__ __attribute__((aligned(16))) unsigned short g_Wb[NTYPES * DIM * DIM]; // [t][o][d], 256 KiB

__device__ __forceinline__ unsigned int f2b(float f) {
    unsigned int u = __float_as_uint(f);
    u += 0x7FFFu + ((u >> 16) & 1u);   // round-to-nearest-even
    return u >> 16;
}
#define BF_LO(u) __uint_as_float((unsigned int)(u) << 16)
#define BF_HI(u) __uint_as_float((unsigned int)(u) & 0xFFFF0000u)

__device__ __forceinline__ bf16x8 cvt8(const f32x4 lo, const f32x4 hi) {
    bf16x8 r;
    r[0] = (__bf16)lo[0]; r[1] = (__bf16)lo[1]; r[2] = (__bf16)lo[2]; r[3] = (__bf16)lo[3];
    r[4] = (__bf16)hi[0]; r[5] = (__bf16)hi[1]; r[6] = (__bf16)hi[2]; r[7] = (__bf16)hi[3];
    return r;
}

// ---------------- fused prep kernel ----------------
// blocks 0..63: xT transpose+convert; blocks 64..95: W convert.

__global__ void prep_all(const float* __restrict__ x, const float* __restrict__ w) {
    const int tid = threadIdx.x;
    if (blockIdx.x < 64) {
        int n = blockIdx.x * 256 + tid;
        const float* row = x + (size_t)n * DIM;
#pragma unroll
        for (int d0 = 0; d0 < DIM; d0 += 4) {
            float4 v = *(const float4*)(row + d0);
            g_xT[(d0 + 0) * N_NODES + n] = (unsigned short)f2b(v.x);
            g_xT[(d0 + 1) * N_NODES + n] = (unsigned short)f2b(v.y);
            g_xT[(d0 + 2) * N_NODES + n] = (unsigned short)f2b(v.z);
            g_xT[(d0 + 3) * N_NODES + n] = (unsigned short)f2b(v.w);
        }
    } else {
        int base = ((blockIdx.x - 64) * 256 + tid) * 16;
#pragma unroll
        for (int j = 0; j < 4; ++j) {
            float4 v = *(const float4*)(w + base + j * 4);
            ushort4 o;
            o.x = (unsigned short)f2b(v.x); o.y = (unsigned short)f2b(v.y);
            o.z = (unsigned short)f2b(v.z); o.w = (unsigned short)f2b(v.w);
            *(ushort4*)(g_Wb + base + j * 4) = o;
        }
    }
}

// ---------------- main fused kernel ----------------

#define ABYTES 32768   // A tile: 64 rows x 512B (f32; 32x16B chunks/row)
#define XBYTES 32768   // X tile: 128 d-rows x 256B (bf16; 16x16B chunks/row)

#define GLOAD16(g, l) __builtin_amdgcn_global_load_lds(                         \
    (const __attribute__((address_space(1))) unsigned int*)(g),                 \
    (__attribute__((address_space(3))) unsigned int*)(l), 16, 0, 0)

// 8 DMA calls per wave per tile: A j=0..3 (16 rows each), X j=0..3 (32 d each)
#define DMA8(Ab, Xb) do {                                                       \
    GLOAD16(gA0, (Ab) + wq);          GLOAD16(gA1, (Ab) +  8192 + wq);          \
    GLOAD16(gA2, (Ab) + 16384 + wq);  GLOAD16(gA3, (Ab) + 24576 + wq);          \
    GLOAD16(gX0, (Xb) + wq);          GLOAD16(gX1, (Xb) +  8192 + wq);          \
    GLOAD16(gX2, (Xb) + 16384 + wq);  GLOAD16(gX3, (Xb) + 24576 + wq);          \
    gA0 += BK; gA1 += BK; gA2 += BK; gA3 += BK;                                 \
    gX0 += BK; gX1 += BK; gX2 += BK; gX3 += BK;                                 \
} while (0)

// one k-substep (32 k): A frag (2 f32x4 + cvt) x 4 X frags -> 4 MFMA
#define KSUB(Ab, Xb, kc, xo) do {                                               \
    f32x4 _e = *(const f32x4*)((Ab) + aoE + (kc) * 128);                        \
    f32x4 _o = *(const f32x4*)((Ab) + aoO + (kc) * 128);                        \
    bf16x8 _a = cvt8(_e, _o);                                                   \
    bf16x8 _b0 = *(const bf16x8*)((Xb) + (xo));                                 \
    bf16x8 _b1 = *(const bf16x8*)((Xb) + (xo) + 4096);                          \
    bf16x8 _b2 = *(const bf16x8*)((Xb) + (xo) + 8192);                          \
    bf16x8 _b3 = *(const bf16x8*)((Xb) + (xo) + 12288);                         \
    acc0 = __builtin_amdgcn_mfma_f32_16x16x32_bf16(_a, _b0, acc0, 0, 0, 0);     \
    acc1 = __builtin_amdgcn_mfma_f32_16x16x32_bf16(_a, _b1, acc1, 0, 0, 0);     \
    acc2 = __builtin_amdgcn_mfma_f32_16x16x32_bf16(_a, _b2, acc2, 0, 0, 0);     \
    acc3 = __builtin_amdgcn_mfma_f32_16x16x32_bf16(_a, _b3, acc3, 0, 0, 0);     \
} while (0)

#define COMPUTE(Ab, Xb) do {        \
    KSUB(Ab, Xb, 0, xo0);           \
    KSUB(Ab, Xb, 1, xo1);           \
    KSUB(Ab, Xb, 2, xo2);           \
    KSUB(Ab, Xb, 3, xo3);           \
} while (0)

// phase: vmcnt(8) [tile t's 8 done, t+1's 8 in flight] -> barrier -> compute t
// -> barrier (all waves done reading) -> issue t+2 into the freed buffer.
#define PHASE_I(Ac, Xc) do {                                 \
    asm volatile("s_waitcnt vmcnt(8)" ::: "memory");         \
    __builtin_amdgcn_s_barrier();                            \
    COMPUTE(Ac, Xc);                                         \
    asm volatile("s_barrier" ::: "memory");                  \
    DMA8(Ac, Xc);                                            \
} while (0)

__global__ __launch_bounds__(512, 1) void gconv_main(
    const float* __restrict__ adj,
    const int* __restrict__ types,
    float* __restrict__ out)
{
    __shared__ __align__(16) unsigned char lds[2 * (ABYTES + XBYTES)]; // 131072 B
    unsigned char* Ab0 = lds;
    unsigned char* Ab1 = lds + ABYTES;
    unsigned char* Xb0 = lds + 2 * ABYTES;
    unsigned char* Xb1 = Xb0 + XBYTES;

    const int tid  = threadIdx.x;
    const int w    = tid >> 6;          // 0..7
    const int l    = tid & 63;
    const int m0   = blockIdx.x * BM;

    const int mrow = (w & 3) * 16;      // wave's 16 output rows (of 64)
    const int ncol = (w >> 2) * 64;     // wave's 64 output cols (of 128)

    f32x4 acc0 = {}, acc1 = {}, acc2 = {}, acc3 = {};

    // ---- DMA source pointers (pre-swizzled so linear LDS dest + XOR'd read
    // offsets form a consistent involution, m173/T2) ----
    // A call j: LDS row = j*16 + 2w + (l>>5) (512B rows), phys chunk = l&31,
    //           source logical chunk = (l&31) ^ (row&7)
    const int arw = 2 * w + (l >> 5);
    const float* gA0 = adj + (size_t)(m0 + arw) * N_NODES
                     + (((l & 31) ^ (arw & 7)) << 2);
    const float* gA1 = gA0 + (size_t)16 * N_NODES;
    const float* gA2 = gA0 + (size_t)32 * N_NODES;
    const float* gA3 = gA0 + (size_t)48 * N_NODES;
    // X call j: LDS d-row = j*32 + 4w + (l>>4) (256B rows), phys chunk = l&15,
    //           source logical chunk = (l&15) ^ (d&7)
    const int xdw = 4 * w + (l >> 4);
    const unsigned short* gX0 = g_xT + (size_t)xdw * N_NODES
                              + (((l & 15) ^ (xdw & 7)) << 3);
    const unsigned short* gX1 = gX0 + (size_t)32 * N_NODES;
    const unsigned short* gX2 = gX0 + (size_t)64 * N_NODES;
    const unsigned short* gX3 = gX0 + (size_t)96 * N_NODES;
    const int wq = w << 10;             // wave's 1KB slot within each 8KB round

    // ---- compute-side byte offsets (XOR matches the source swizzle) ----
    // A: row r = mrow+(l&15); logical chunk (kc*8 + 2*(l>>4)) ^ (r&7), r&7 = l&7
    const int r    = mrow + (l & 15);
    const int aoE  = r * 512 + ((((l >> 4) * 2)     ^ (l & 7)) << 4);
    const int aoO  = r * 512 + ((((l >> 4) * 2 + 1) ^ (l & 7)) << 4);
    // X: d = ncol + nt*16 + (l&15); phys chunk = (kc*4 + (l>>4)) ^ (d&7), d&7 = l&7
    const int dd   = (ncol + (l & 15)) * 256;
    const int xo0  = dd + ((( 0 + (l >> 4)) ^ (l & 7)) << 4);
    const int xo1  = dd + ((( 4 + (l >> 4)) ^ (l & 7)) << 4);
    const int xo2  = dd + ((( 8 + (l >> 4)) ^ (l & 7)) << 4);
    const int xo3  = dd + (((12 + (l >> 4)) ^ (l & 7)) << 4);

    // ---- prologue: tiles 0 and 1 in flight (16 calls/wave outstanding) ----
    DMA8(Ab0, Xb0);
    DMA8(Ab1, Xb1);

    // ---- 128 phases: 63 x 2 issuing (t=0..125) + 2 tail ----
    for (int i = 0; i < 63; ++i) {
        PHASE_I(Ab0, Xb0);              // t even: compute buf0, issue t+2 -> buf0
        PHASE_I(Ab1, Xb1);              // t odd
    }
    asm volatile("s_waitcnt vmcnt(8)" ::: "memory");   // t=126
    __builtin_amdgcn_s_barrier();
    COMPUTE(Ab0, Xb0);
    asm volatile("s_waitcnt vmcnt(0)" ::: "memory");   // t=127
    __builtin_amdgcn_s_barrier();
    COMPUTE(Ab1, Xb1);
    __syncthreads();                    // drain before reusing LDS as agg

    // ---- epilogue: acc -> LDS agg (f32), then per-row W[type] dots ----
    float* agg = (float*)lds;   // [64][132] = 33792 B
#pragma unroll
    for (int rr = 0; rr < 4; ++rr) {
        const int gr = (mrow + (l >> 4) * 4 + rr) * 132 + ncol + (l & 15);
        agg[gr +  0] = acc0[rr];
        agg[gr + 16] = acc1[rr];
        agg[gr + 32] = acc2[rr];
        agg[gr + 48] = acc3[rr];
    }
    __syncthreads();

    const int rbase = w * 8;   // 8 rows per wave
    for (int rr = 0; rr < 8; ++rr) {
        const int rw = rbase + rr;
        const int nn = m0 + rw;
        const int ty = types[nn];                      // wave-uniform
        const unsigned short* Wt = g_Wb + ty * (DIM * DIM);
        const int o0 = l * 2;
        const float* aggRow = agg + rw * 132;
        float s0 = 0.f, s1 = 0.f;
#pragma unroll
        for (int d0 = 0; d0 < DIM; d0 += 8) {
            float4 ga = *(const float4*)(aggRow + d0);
            float4 gb = *(const float4*)(aggRow + d0 + 4);
            uint4 wa = *(const uint4*)(Wt + o0 * DIM + d0);
            uint4 wb = *(const uint4*)(Wt + (o0 + 1) * DIM + d0);
            s0 += ga.x * BF_LO(wa.x) + ga.y * BF_HI(wa.x) + ga.z * BF_LO(wa.y) + ga.w * BF_HI(wa.y);
            s0 += gb.x * BF_LO(wa.z) + gb.y * BF_HI(wa.z) + gb.z * BF_LO(wa.w) + gb.w * BF_HI(wa.w);
            s1 += ga.x * BF_LO(wb.x) + ga.y * BF_HI(wb.x) + ga.z * BF_LO(wb.y) + ga.w * BF_HI(wb.y);
            s1 += gb.x * BF_LO(wb.z) + gb.y * BF_HI(wb.z) + gb.z * BF_LO(wb.w) + gb.w * BF_HI(wb.w);
        }
        float2 res; res.x = s0; res.y = s1;
        *(float2*)(out + (size_t)nn * DIM + o0) = res;
    }
}

// ---------------- launch ----------------

extern "C" void kernel_launch(void* const* d_in, const int* in_sizes, int n_in,
                              void* d_out, int out_size, void* d_ws, size_t ws_size,
                              hipStream_t stream) {
    const float* x     = (const float*)d_in[0];
    const int*   types = (const int*)d_in[1];
    const float* adj   = (const float*)d_in[2];
    const float* wt    = (const float*)d_in[3];
    float* out = (float*)d_out;

    hipLaunchKernelGGL(prep_all, dim3(96), dim3(256), 0, stream, x, wt);
    hipLaunchKernelGGL(gconv_main, dim3(N_NODES / BM), dim3(512), 0, stream, adj, types, out);
}